// Round 1
// 1683.191 us; speedup vs baseline: 1.0392x; 1.0392x over previous
//
#include <hip/hip_runtime.h>

#define N_DATA    500000
#define FEAT_DIM  512
#define NUM_CLASS 10000
#define BATCH     8192
#define MOMENTUM  0.9f

#define BITMAP_WORDS 15625   // ceil(N_DATA / 32)
#define FUSED_GRID   2048
#define UPD_BLOCKS   (FUSED_GRID / 8)                  // 256 (blockIdx & 7 == 0)
#define CPY_BLOCKS   (FUSED_GRID - UPD_BLOCKS)         // 1792
#define ROWS_PER_UPD (BATCH / UPD_BLOCKS)              // 32 rows per update block

// ---------------- Kernel 1: bitmap build (block 0) + class_sums copy ----------------
__global__ __launch_bounds__(256) void prep_kernel(const float4* __restrict__ cls_src,
                                                   float4*       __restrict__ cls_dst,
                                                   const int*    __restrict__ idx,
                                                   unsigned int* __restrict__ bitmap) {
    const int t = threadIdx.x;
    if (blockIdx.x == 0) {
        // zero the bitmap, then set one bit per updated row
        for (int i = t; i < BITMAP_WORDS; i += 256) bitmap[i] = 0u;
        __syncthreads();
        for (int i = t; i < BATCH; i += 256) {
            const int r = idx[i];
            atomicOr(&bitmap[r >> 5], 1u << (r & 31));
        }
    } else {
        const long long n4     = (long long)NUM_CLASS * (FEAT_DIM / 4);  // 1,280,000
        const long long stride = (long long)(gridDim.x - 1) * 256;
        long long i = (long long)(blockIdx.x - 1) * 256 + t;
        for (; i < n4; i += stride) cls_dst[i] = cls_src[i];
    }
}

// ---------------- Kernel 2: fused copy (skip updated rows) || update ----------------
// Roles interleaved so update blocks co-run with copy blocks across all CUs.
__global__ __launch_bounds__(256) void fused_kernel(const float4* __restrict__ batch,   // [BATCH, 128]
                                                    const float4* __restrict__ lat,     // [N_DATA, 128]
                                                    const int*    __restrict__ targets,
                                                    const int*    __restrict__ idx,
                                                    const unsigned int* __restrict__ bitmap,
                                                    float4*       __restrict__ out_lat, // [N_DATA, 128]
                                                    float*        __restrict__ out_cls) // [NUM_CLASS, 512]
{
    const int t = threadIdx.x;
    const int b = blockIdx.x;

    if ((b & 7) == 0) {
        // ---- update role: 32 batch rows, 1 row per wave per pass, pure-shuffle reduce ----
        const int upd = b >> 3;      // 0..255
        const int w   = t >> 6;      // wave id 0..3
        const int l   = t & 63;      // lane
        #pragma unroll
        for (int pass = 0; pass < ROWS_PER_UPD / 4; ++pass) {
            const int row = upd * ROWS_PER_UPD + pass * 4 + w;   // 0..8191
            const int src = idx[row];
            const int cls = targets[row];
            const long long bb = (long long)row * 128 + l;   // lane covers f4 l and l+64
            const long long mb = (long long)src * 128 + l;

            const float4 b0 = batch[bb], b1 = batch[bb + 64];
            const float4 m0 = lat[mb],   m1 = lat[mb + 64];

            float4 v0, v1;
            v0.x = m0.x * (1.0f - MOMENTUM) + b0.x * MOMENTUM;
            v0.y = m0.y * (1.0f - MOMENTUM) + b0.y * MOMENTUM;
            v0.z = m0.z * (1.0f - MOMENTUM) + b0.z * MOMENTUM;
            v0.w = m0.w * (1.0f - MOMENTUM) + b0.w * MOMENTUM;
            v1.x = m1.x * (1.0f - MOMENTUM) + b1.x * MOMENTUM;
            v1.y = m1.y * (1.0f - MOMENTUM) + b1.y * MOMENTUM;
            v1.z = m1.z * (1.0f - MOMENTUM) + b1.z * MOMENTUM;
            v1.w = m1.w * (1.0f - MOMENTUM) + b1.w * MOMENTUM;

            float ss = v0.x * v0.x + v0.y * v0.y + v0.z * v0.z + v0.w * v0.w
                     + v1.x * v1.x + v1.y * v1.y + v1.z * v1.z + v1.w * v1.w;
            #pragma unroll
            for (int off = 32; off > 0; off >>= 1) ss += __shfl_xor(ss, off, 64);
            const float inv = 1.0f / sqrtf(ss);

            v0.x *= inv; v0.y *= inv; v0.z *= inv; v0.w *= inv;
            v1.x *= inv; v1.y *= inv; v1.z *= inv; v1.w *= inv;

            out_lat[mb]      = v0;
            out_lat[mb + 64] = v1;

            float* cp = out_cls + (long long)cls * FEAT_DIM + 4 * l;
            atomicAdd(cp + 0, v0.x);
            atomicAdd(cp + 1, v0.y);
            atomicAdd(cp + 2, v0.z);
            atomicAdd(cp + 3, v0.w);
            atomicAdd(cp + 256 + 0, v1.x);
            atomicAdd(cp + 256 + 1, v1.y);
            atomicAdd(cp + 256 + 2, v1.z);
            atomicAdd(cp + 256 + 3, v1.w);
        }
    } else {
        // ---- copy role: grid-stride float4 copy of lat -> out_lat, skipping updated rows ----
        const int cid = b - (b >> 3) - 1;                         // compact id 0..CPY_BLOCKS-1
        const long long n4     = (long long)N_DATA * 128;         // 64,000,000
        const long long stride = (long long)CPY_BLOCKS * 256;
        long long i = (long long)cid * 256 + t;
        for (; i < n4; i += stride) {
            const int row = (int)(i >> 7);
            if ((bitmap[row >> 5] >> (row & 31)) & 1u) continue;  // wave-uniform (row spans 2 waves)
            out_lat[i] = lat[i];
        }
    }
}

// ---------------- Fallback path (baseline), used if workspace is too small ----------------
__global__ __launch_bounds__(256) void copy_f4_kernel(const float4* __restrict__ src,
                                                      float4* __restrict__ dst,
                                                      long long n4) {
    long long i = (long long)blockIdx.x * blockDim.x + threadIdx.x;
    long long stride = (long long)gridDim.x * blockDim.x;
    for (; i < n4; i += stride) dst[i] = src[i];
}

__global__ __launch_bounds__(128) void update_kernel(const float4* __restrict__ batch,
                                                     const float4* __restrict__ lat,
                                                     const int*    __restrict__ targets,
                                                     const int*    __restrict__ idx,
                                                     float4*       __restrict__ out_lat,
                                                     float*        __restrict__ out_cls)
{
    const int row = blockIdx.x;
    const int t   = threadIdx.x;
    const int src_row = idx[row];
    const int cls     = targets[row];

    const float4 bv = batch[(long long)row * 128 + t];
    const float4 m  = lat[(long long)src_row * 128 + t];

    float4 v;
    v.x = m.x * (1.0f - MOMENTUM) + bv.x * MOMENTUM;
    v.y = m.y * (1.0f - MOMENTUM) + bv.y * MOMENTUM;
    v.z = m.z * (1.0f - MOMENTUM) + bv.z * MOMENTUM;
    v.w = m.w * (1.0f - MOMENTUM) + bv.w * MOMENTUM;

    float ss = v.x * v.x + v.y * v.y + v.z * v.z + v.w * v.w;
    #pragma unroll
    for (int off = 32; off > 0; off >>= 1) ss += __shfl_down(ss, off, 64);

    __shared__ float partial[2];
    if ((t & 63) == 0) partial[t >> 6] = ss;
    __syncthreads();
    const float total = partial[0] + partial[1];
    const float inv = 1.0f / sqrtf(total);

    v.x *= inv; v.y *= inv; v.z *= inv; v.w *= inv;
    out_lat[(long long)src_row * 128 + t] = v;

    float* cp = out_cls + (long long)cls * FEAT_DIM + t * 4;
    atomicAdd(cp + 0, v.x);
    atomicAdd(cp + 1, v.y);
    atomicAdd(cp + 2, v.z);
    atomicAdd(cp + 3, v.w);
}

extern "C" void kernel_launch(void* const* d_in, const int* in_sizes, int n_in,
                              void* d_out, int out_size, void* d_ws, size_t ws_size,
                              hipStream_t stream) {
    const float* batch    = (const float*)d_in[0];  // [BATCH, FEAT_DIM]
    const float* lat      = (const float*)d_in[1];  // [N_DATA, FEAT_DIM]
    const float* cls_sums = (const float*)d_in[2];  // [NUM_CLASS, FEAT_DIM]
    const int*   targets  = (const int*)d_in[3];    // [BATCH]
    const int*   idx      = (const int*)d_in[4];    // [BATCH]

    float* out_lat = (float*)d_out;                              // [N_DATA, FEAT_DIM]
    float* out_cls = out_lat + (long long)N_DATA * FEAT_DIM;     // [NUM_CLASS, FEAT_DIM]

    if (ws_size >= (size_t)(BITMAP_WORDS * sizeof(unsigned int))) {
        unsigned int* bitmap = (unsigned int*)d_ws;

        // 1) bitmap of updated rows + class_sums copy (2561 blocks: 1 bitmap + 2560 copy)
        prep_kernel<<<2561, 256, 0, stream>>>((const float4*)cls_sums, (float4*)out_cls,
                                              idx, bitmap);

        // 2) fused: copy lat->out_lat (skipping updated rows) CONCURRENT with
        //    gather/blend/normalize/scatter/segment-sum (race-free via bitmap)
        fused_kernel<<<FUSED_GRID, 256, 0, stream>>>((const float4*)batch, (const float4*)lat,
                                                     targets, idx, bitmap,
                                                     (float4*)out_lat, out_cls);
    } else {
        // Fallback: baseline 3-kernel path (no workspace required)
        {
            long long n4 = (long long)N_DATA * FEAT_DIM / 4;
            copy_f4_kernel<<<8192, 256, 0, stream>>>((const float4*)lat, (float4*)out_lat, n4);
        }
        {
            long long n4 = (long long)NUM_CLASS * FEAT_DIM / 4;
            copy_f4_kernel<<<2560, 256, 0, stream>>>((const float4*)cls_sums, (float4*)out_cls, n4);
        }
        update_kernel<<<BATCH, 128, 0, stream>>>((const float4*)batch, (const float4*)lat,
                                                 targets, idx,
                                                 (float4*)out_lat, out_cls);
    }
}